// Round 2
// baseline (227.799 us; speedup 1.0000x reference)
//
#include <hip/hip_runtime.h>

#define TT 16384      // total tokens
#define DD 2048       // d_model
#define EE 64         // experts
#define TM 64         // tokens per block
#define BK 16         // K-step
#define NSTEP (DD/BK) // 128
#define NBLK (TT/TM)  // 256
#define CAP 512u      // expert capacity (keep if 1-based position < CAP)

__device__ __forceinline__ bool pair_gt(float va, int ia, float vb, int ib) {
    // jax.lax.top_k ordering: higher value wins; tie -> lower index wins
    return (va > vb) || (va == vb && ia < ib);
}

// k1: fused gate GEMM (f32, deterministic per-thread accumulation) + softmax
//     + top2 + per-block counts/probsums/z-partials.
// Layout: 512 threads = 8 waves. lane = token (64/block), wave = 8 experts.
// W read via wave-uniform s_load (SGPR operand in v_fmac), X via LDS
// transposed tile Xs[tok][stride 17] (odd stride -> conflict-free).
__global__ __launch_bounds__(512) void k1_router(
    const float* __restrict__ X, const float* __restrict__ W,
    const float* __restrict__ bias,
    uint4* __restrict__ top2, unsigned* __restrict__ counts,
    float* __restrict__ probsum, float* __restrict__ zsum)
{
    __shared__ float Xs[TM][17];   // X tile, [token][k], stride 17
    __shared__ float Ls[TM][68];   // logits [token][expert], pad to 68 (16B-aligned rows)
    __shared__ float lseS[TM];
    __shared__ float ps2[8][EE];
    __shared__ unsigned cnt[EE];

    const int tid = threadIdx.x;
    const int b = blockIdx.x;
    const int tok0 = b * TM;
    const int w = tid >> 6;                 // wave id 0..7
    const int lane = tid & 63;              // token within tile
    const int we0 = __builtin_amdgcn_readfirstlane(w * 8);   // expert base (SGPR)

    // staging map: thread -> (row sr, k-pair sc); wave = 8 rows x 64B contiguous
    const int sr = tid >> 3;
    const int sc = (tid & 7) * 2;
    const float* gX = X + (size_t)(tok0 + sr) * DD + sc;
    const float* Wb = W + (size_t)we0 * DD;  // uniform pointer -> s_load

    float acc[8] = {0.f,0.f,0.f,0.f,0.f,0.f,0.f,0.f};

    float2 xrA = *(const float2*)(gX + 0 * BK);
    float2 xrB = *(const float2*)(gX + 1 * BK);

    for (int s = 0; s < NSTEP; ++s) {
        const int k0 = s * BK;
        __syncthreads();                    // prev step's Xs reads complete
        Xs[sr][sc]     = xrA.x;
        Xs[sr][sc + 1] = xrA.y;
        xrA = xrB;
        if (s + 2 < NSTEP) xrB = *(const float2*)(gX + (s + 2) * BK);
        __syncthreads();                    // Xs ready
        #pragma unroll
        for (int kc = 0; kc < BK; kc += 4) {
            float4 wv[8];
            #pragma unroll
            for (int e = 0; e < 8; ++e)
                wv[e] = *(const float4*)(Wb + e * DD + k0 + kc);  // s_load_dwordx4
            const float x0 = Xs[lane][kc + 0];
            const float x1 = Xs[lane][kc + 1];
            const float x2 = Xs[lane][kc + 2];
            const float x3 = Xs[lane][kc + 3];
            #pragma unroll
            for (int e = 0; e < 8; ++e) {
                acc[e] = fmaf(x0, wv[e].x, acc[e]);
                acc[e] = fmaf(x1, wv[e].y, acc[e]);
                acc[e] = fmaf(x2, wv[e].z, acc[e]);
                acc[e] = fmaf(x3, wv[e].w, acc[e]);
            }
        }
    }

    #pragma unroll
    for (int e = 0; e < 8; ++e) acc[e] += bias[we0 + e];

    if (tid < EE) cnt[tid] = 0;
    // store logits: token=lane, experts we0..we0+7
    *(float4*)&Ls[lane][we0 + 0] = make_float4(acc[0], acc[1], acc[2], acc[3]);
    *(float4*)&Ls[lane][we0 + 4] = make_float4(acc[4], acc[5], acc[6], acc[7]);
    __syncthreads();

    // epilogue: 8 threads per token (o = expert octet)
    const int tok = tid >> 3;
    const int o = tid & 7;
    const float4 va = *(const float4*)&Ls[tok][o * 8 + 0];
    const float4 vb = *(const float4*)&Ls[tok][o * 8 + 4];
    float v[8] = {va.x, va.y, va.z, va.w, vb.x, vb.y, vb.z, vb.w};

    float mx = v[0];
    #pragma unroll
    for (int j = 1; j < 8; ++j) mx = fmaxf(mx, v[j]);
    #pragma unroll
    for (int sft = 1; sft < 8; sft <<= 1) mx = fmaxf(mx, __shfl_xor(mx, sft, 64));
    float sum = 0.f;
    #pragma unroll
    for (int j = 0; j < 8; ++j) sum += expf(v[j] - mx);
    #pragma unroll
    for (int sft = 1; sft < 8; sft <<= 1) sum += __shfl_xor(sum, sft, 64);
    const float lse = mx + logf(sum);

    float v1 = v[0]; int i1 = o * 8;
    float v2 = -3.402823466e38f; int i2 = 0x7fffffff;
    #pragma unroll
    for (int j = 1; j < 8; ++j) {
        const float vv = v[j]; const int e = o * 8 + j;
        if (pair_gt(vv, e, v1, i1)) { v2 = v1; i2 = i1; v1 = vv; i1 = e; }
        else if (pair_gt(vv, e, v2, i2)) { v2 = vv; i2 = e; }
    }
    #pragma unroll
    for (int sft = 1; sft < 8; sft <<= 1) {
        const float ov1 = __shfl_xor(v1, sft, 64); const int oi1 = __shfl_xor(i1, sft, 64);
        const float ov2 = __shfl_xor(v2, sft, 64); const int oi2 = __shfl_xor(i2, sft, 64);
        if (pair_gt(ov1, oi1, v1, i1)) {
            if (pair_gt(v1, i1, ov2, oi2)) { v2 = v1; i2 = i1; }
            else                            { v2 = ov2; i2 = oi2; }
            v1 = ov1; i1 = oi1;
        } else {
            if (pair_gt(ov1, oi1, v2, i2)) { v2 = ov1; i2 = oi1; }
        }
    }
    const float w1 = expf(v1 - lse), w2 = expf(v2 - lse);

    if (o == 0) {
        lseS[tok] = lse;
        top2[tok0 + tok] = make_uint4((unsigned)i1, (unsigned)i2,
                                      __float_as_uint(w1), __float_as_uint(w2));
        atomicAdd(&cnt[i1], 1u);
        atomicAdd(&cnt[i2], 1u);
    }
    __syncthreads();

    // per-expert prob sums (fixed-order partials -> deterministic)
    {
        const int e = tid & 63;
        const int tp = tid >> 6;
        float sme = 0.f;
        for (int t = tp * 8; t < tp * 8 + 8; ++t)
            sme += expf(Ls[t][e] - lseS[t]);
        ps2[tp][e] = sme;
    }
    __syncthreads();
    if (tid < EE) {
        float sacc = 0.f;
        #pragma unroll
        for (int p = 0; p < 8; ++p) sacc += ps2[p][tid];
        probsum[b * EE + tid] = sacc;
        counts[b * EE + tid] = cnt[tid];
    }
    if (tid == 0) {
        float z = 0.f;
        for (int t = 0; t < TM; ++t) z += lseS[t] * lseS[t];
        zsum[b] = z;
    }
}

// k2: per-expert exclusive prefix over the 256 block-chunks (2-pass, 256 thr)
//     + loss. Deterministic fixed-order sums.
__global__ __launch_bounds__(256) void k2_scan(
    const unsigned* __restrict__ counts, const float* __restrict__ probsum,
    const float* __restrict__ zsum, unsigned* __restrict__ base,
    float* __restrict__ loss_out)
{
    __shared__ unsigned pc[4][EE];
    __shared__ float pps[4][EE];
    __shared__ float zz[256];
    const int tid = threadIdx.x;
    const int e = tid & 63, q = tid >> 6;
    const int b0 = q * (NBLK / 4), b1 = b0 + (NBLK / 4);

    unsigned csum = 0; float psum_ = 0.f;
    for (int bb = b0; bb < b1; ++bb) {
        csum += counts[bb * EE + e];
        psum_ += probsum[bb * EE + e];
    }
    pc[q][e] = csum; pps[q][e] = psum_;
    zz[tid] = zsum[tid];              // zsum[b] is already sum of lse^2 per block
    __syncthreads();

    unsigned off = 0;
    for (int qq = 0; qq < q; ++qq) off += pc[qq][e];
    unsigned run = off;
    for (int bb = b0; bb < b1; ++bb) {
        base[bb * EE + e] = run;
        run += counts[bb * EE + e];
    }

    if (q == 0) {   // wave 0 only (uniform)
        const unsigned tot = pc[0][e] + pc[1][e] + pc[2][e] + pc[3][e];
        const float pt = pps[0][e] + pps[1][e] + pps[2][e] + pps[3][e];
        float a = (float)tot * pt;
        #pragma unroll
        for (int sft = 1; sft < 64; sft <<= 1) a += __shfl_xor(a, sft, 64);
        float z4 = zz[tid] + zz[tid + 64] + zz[tid + 128] + zz[tid + 192];
        #pragma unroll
        for (int sft = 1; sft < 64; sft <<= 1) z4 += __shfl_xor(z4, sft, 64);
        if (e == 0) {
            const float Tf = (float)TT;
            loss_out[0] = 0.01f * 64.0f * (a / (Tf * Tf)) + z4 / Tf;
        }
    }
}

// k3: capacity ranking within each 64-token chunk + dense mask/weight writes
__global__ __launch_bounds__(256) void k3_write(
    const uint4* __restrict__ top2, const unsigned* __restrict__ base,
    float* __restrict__ mask_out, float* __restrict__ w_out)
{
    __shared__ unsigned ti1[TM], ti2[TM], tk1[TM], tk2[TM];
    __shared__ float tw1[TM], tw2[TM];
    const int b = blockIdx.x, tid = threadIdx.x;
    if (tid < TM) {
        const uint4 v = top2[b * TM + tid];
        ti1[tid] = v.x; ti2[tid] = v.y;
        tw1[tid] = __uint_as_float(v.z); tw2[tid] = __uint_as_float(v.w);
    }
    __syncthreads();
    if (tid < EE) {
        const unsigned e = (unsigned)tid;
        unsigned cc = base[b * EE + tid];
        for (int i = 0; i < TM; ++i) {   // token order = global cumsum order
            if (ti1[i] == e) { cc++; tk1[i] = (cc < CAP); }
            if (ti2[i] == e) { cc++; tk2[i] = (cc < CAP); }
        }
    }
    __syncthreads();
    const int i = tid >> 2, q = tid & 3;
    const unsigned a1 = ti1[i], a2 = ti2[i];
    const unsigned kp1 = tk1[i], kp2 = tk2[i];
    const float w1 = tw1[i], w2 = tw2[i];
    float om[16], ow[16];
    #pragma unroll
    for (int j = 0; j < 16; ++j) {
        const unsigned e = (unsigned)(q * 16 + j);
        float mv = 0.f, wv = 0.f;
        if (e == a1 && kp1) { mv = 1.f; wv = w1; }
        if (e == a2 && kp2) { mv = 1.f; wv = w2; }
        om[j] = mv; ow[j] = wv;
    }
    float* mrow = mask_out + (size_t)(b * TM + i) * EE + q * 16;
    float* wrow = w_out    + (size_t)(b * TM + i) * EE + q * 16;
    #pragma unroll
    for (int j4 = 0; j4 < 4; ++j4) {
        *(float4*)(mrow + j4 * 4) = make_float4(om[j4*4+0], om[j4*4+1], om[j4*4+2], om[j4*4+3]);
        *(float4*)(wrow + j4 * 4) = make_float4(ow[j4*4+0], ow[j4*4+1], ow[j4*4+2], ow[j4*4+3]);
    }
}

extern "C" void kernel_launch(void* const* d_in, const int* in_sizes, int n_in,
                              void* d_out, int out_size, void* d_ws, size_t ws_size,
                              hipStream_t stream)
{
    const float* X    = (const float*)d_in[0];
    const float* W    = (const float*)d_in[1];
    const float* bias = (const float*)d_in[2];
    float* out = (float*)d_out;
    float* mask_out = out;
    float* w_out    = out + (size_t)TT * EE;
    float* loss_out = out + (size_t)2 * TT * EE;

    char* ws = (char*)d_ws;
    uint4*    top2    = (uint4*)ws;                               // 256 KB
    unsigned* counts  = (unsigned*)(ws + 262144);                 // 64 KB
    float*    probsum = (float*)(ws + 262144 + 65536);            // 64 KB
    float*    zsum    = (float*)(ws + 262144 + 131072);           // 1 KB (pad 4K)
    unsigned* base    = (unsigned*)(ws + 262144 + 131072 + 4096); // 64 KB

    k1_router<<<NBLK, 512, 0, stream>>>(X, W, bias, top2, counts, probsum, zsum);
    k2_scan<<<1, 256, 0, stream>>>(counts, probsum, zsum, base, loss_out);
    k3_write<<<NBLK, 256, 0, stream>>>(top2, base, mask_out, w_out);
}